// Round 1
// baseline (9449.941 us; speedup 1.0000x reference)
//
#include <hip/hip_runtime.h>
#include <stdint.h>
#include <stddef.h>

// LSTM_63488206569533: B=128, T=1024, I=256, H=512, fp32 in/out.
// Persistent kernel: 256 WGs (8 batch-groups x 32 unit-slices), one per CU.
// Each WG: 16 batches x 16 hidden units -> 64 gate rows, K=768 (x|h).
// W rows live in MFMA B-fragment registers (bf16). h exchanged via global
// double buffer with per-group monotonic counters (agent-scope fences).

#define Bn   128
#define Tn   1024
#define In   256
#define Hn   512
#define PM   8     // batch groups
#define PN   32    // unit slices
#define BPW  16    // batches per WG
#define UPW  16    // units per WG
#define APAD 776   // padded A row length in bf16 elems (1552 B, 16B-aligned rows)

typedef float f4 __attribute__((ext_vector_type(4)));
typedef short s8 __attribute__((ext_vector_type(8)));

static __device__ __forceinline__ short f2bf(float f) {
  union { float f; unsigned u; } v; v.f = f;
  unsigned u = v.u;
  return (short)((u + 0x7FFFu + ((u >> 16) & 1u)) >> 16);  // RNE
}

__global__ __launch_bounds__(256, 1)
void lstm_persist(const float* __restrict__ x,
                  const float* __restrict__ W_ih,
                  const float* __restrict__ W_hh,
                  const float* __restrict__ b_ih,
                  const float* __restrict__ b_hh,
                  const float* __restrict__ fc_w,
                  const float* __restrict__ fc_b,
                  float* __restrict__ out,
                  int* __restrict__ cnt,     // [PM] padded to 64B each
                  short* __restrict__ hbuf)  // [2][Bn][Hn] bf16 bits
{
  const int tid  = threadIdx.x;
  const int wave = tid >> 6;    // 0..3  == gate type (i,f,g,o)
  const int lane = tid & 63;
  const int n16  = lane & 15;   // MFMA: batch row (A) / gate col (B)
  const int q    = lane >> 4;   // MFMA quad -> k-subblock
  const int bg   = blockIdx.x & 7;   // batch group (likely same-XCD cohort)
  const int ns   = blockIdx.x >> 3;  // unit slice 0..31

  __shared__ short A_lds[16 * APAD];      // [batch 16][k 768(+pad)] bf16
  __shared__ float gate_lds[4 * 256];     // [gate 4][batch 16][unit 16]

  // ---- one-time: preload this wave's 16 W rows into B-fragments (bf16) ----
  s8 bfrag[24];
  {
    const int grow = wave * Hn + ns * UPW + n16;  // global gate row in [0,4H)
#pragma unroll
    for (int kk = 0; kk < 24; ++kk) {
      const float* p = (kk < 8)
        ? (W_ih + (size_t)grow * In + kk * 32 + q * 8)
        : (W_hh + (size_t)grow * Hn + (kk - 8) * 32 + q * 8);
      f4 lo = ((const f4*)p)[0];
      f4 hi = ((const f4*)p)[1];
      s8 b;
      b[0]=f2bf(lo[0]); b[1]=f2bf(lo[1]); b[2]=f2bf(lo[2]); b[3]=f2bf(lo[3]);
      b[4]=f2bf(hi[0]); b[5]=f2bf(hi[1]); b[6]=f2bf(hi[2]); b[7]=f2bf(hi[3]);
      bfrag[kk] = b;
    }
  }

  // ---- elementwise-phase mapping: tid -> (batch em, unit en) ----
  const int em  = tid >> 4;
  const int en  = tid & 15;
  const int ug  = ns * UPW + en;     // global unit
  const int bgl = bg * BPW + em;     // global batch
  const float bia = b_ih[ug]        + b_hh[ug];
  const float bfa = b_ih[Hn + ug]   + b_hh[Hn + ug];
  const float bga = b_ih[2*Hn + ug] + b_hh[2*Hn + ug];
  const float boa = b_ih[3*Hn + ug] + b_hh[3*Hn + ug];

  int*   mycnt = cnt + bg * 16;      // 64B-padded per group, monotonic
  short* hb0   = hbuf;
  short* hb1   = hbuf + Bn * Hn;

  const float* xbase = x + (size_t)bgl * Tn * In + en * 16;
  const short* aptr  = A_lds + n16 * APAD + q * 8;

  float creg = 0.f, hreg = 0.f;

  for (int t = 0; t < Tn; ++t) {
    // (1) stage x_t -> A_lds[:, 0:256] (fp32 -> bf16), no dependence on h
    {
      const f4* xp = (const f4*)(xbase + (size_t)t * In);
      f4 a = xp[0], b = xp[1], c = xp[2], d = xp[3];
      s8 lo, hi;
      lo[0]=f2bf(a[0]); lo[1]=f2bf(a[1]); lo[2]=f2bf(a[2]); lo[3]=f2bf(a[3]);
      lo[4]=f2bf(b[0]); lo[5]=f2bf(b[1]); lo[6]=f2bf(b[2]); lo[7]=f2bf(b[3]);
      hi[0]=f2bf(c[0]); hi[1]=f2bf(c[1]); hi[2]=f2bf(c[2]); hi[3]=f2bf(c[3]);
      hi[4]=f2bf(d[0]); hi[5]=f2bf(d[1]); hi[6]=f2bf(d[2]); hi[7]=f2bf(d[3]);
      s8* dst = (s8*)(A_lds + em * APAD + en * 16);
      dst[0] = lo; dst[1] = hi;
    }
    __syncthreads();

    // (2) x-part MFMAs while (possibly) waiting on producers
    f4 acc = {0.f, 0.f, 0.f, 0.f};
#pragma unroll
    for (int kk = 0; kk < 8; ++kk) {
      s8 a = *(const s8*)(aptr + kk * 32);
      acc = __builtin_amdgcn_mfma_f32_16x16x32_bf16(a, bfrag[kk], acc, 0, 0, 0);
    }

    if (t > 0) {
      // (3) wait for all 32 slices of this batch group to have posted h_t
      if (tid == 0) {
        const int target = PN * t;
        while (__hip_atomic_load(mycnt, __ATOMIC_RELAXED, __HIP_MEMORY_SCOPE_AGENT) < target)
          __builtin_amdgcn_s_sleep(1);
        __builtin_amdgcn_fence(__ATOMIC_ACQUIRE, "agent");  // inv L1/L2 before h loads
      }
      __syncthreads();
      // (4) stage h_t -> A_lds[:, 256:768]
      {
        const short* hcur = ((t & 1) ? hb1 : hb0);
        const s8* hp = (const s8*)(hcur + (size_t)bgl * Hn + en * 32);
        s8 h0 = hp[0], h1 = hp[1], h2 = hp[2], h3 = hp[3];
        s8* dst = (s8*)(A_lds + em * APAD + 256 + en * 32);
        dst[0] = h0; dst[1] = h1; dst[2] = h2; dst[3] = h3;
      }
      __syncthreads();
      // (5) h-part MFMAs
#pragma unroll
      for (int kk = 8; kk < 24; ++kk) {
        s8 a = *(const s8*)(aptr + kk * 32);
        acc = __builtin_amdgcn_mfma_f32_16x16x32_bf16(a, bfrag[kk], acc, 0, 0, 0);
      }
    }
    // t==0: h_0 == 0, recurrent contribution is zero -> skip entirely.

    // (6) exchange gates through LDS (C-layout: row=(q*4+r)=batch, col=n16=unit)
#pragma unroll
    for (int r = 0; r < 4; ++r)
      gate_lds[wave * 256 + (q * 4 + r) * 16 + n16] = acc[r];
    __syncthreads();

    // (7) per-(batch,unit) LSTM cell update; c stays in a register
    {
      float zi = gate_lds[tid]       + bia;
      float zf = gate_lds[256 + tid] + bfa;
      float zg = gate_lds[512 + tid] + bga;
      float zo = gate_lds[768 + tid] + boa;
      float gi = 1.f / (1.f + __expf(-zi));
      float gf = 1.f / (1.f + __expf(-zf));
      float gg = 2.f / (1.f + __expf(-2.f * zg)) - 1.f;   // tanh
      float go = 1.f / (1.f + __expf(-zo));
      creg = gf * creg + gi * gg;
      float tc = 2.f / (1.f + __expf(-2.f * creg)) - 1.f; // tanh(c)
      hreg = go * tc;
      short* hnxt = (((t + 1) & 1) ? hb1 : hb0);
      hnxt[(size_t)bgl * Hn + ug] = f2bf(hreg);
    }
    __syncthreads();  // barrier drains vmcnt(0): all h-stores complete in L2
    if (tid == 0) {
      __builtin_amdgcn_fence(__ATOMIC_RELEASE, "agent");  // wbl2: flush to device scope
      __hip_atomic_fetch_add(mycnt, 1, __ATOMIC_RELAXED, __HIP_MEMORY_SCOPE_AGENT);
    }
  }

  // ---- epilogue: out[b] = sum_u hT[b,u] * fc_w[u] + fc_b ----
  float partial = hreg * fc_w[ug];
#pragma unroll
  for (int off = 1; off < 16; off <<= 1)
    partial += __shfl_xor(partial, off, 64);   // reduce over the 16 units
  if (en == 0) {
    if (ns == 0) partial += fc_b[0];           // fc_b exactly once per batch
    atomicAdd(&out[bgl], partial);
  }
}

extern "C" void kernel_launch(void* const* d_in, const int* in_sizes, int n_in,
                              void* d_out, int out_size, void* d_ws, size_t ws_size,
                              hipStream_t stream) {
  const float* x    = (const float*)d_in[0];
  const float* W_ih = (const float*)d_in[1];
  const float* W_hh = (const float*)d_in[2];
  const float* b_ih = (const float*)d_in[3];
  const float* b_hh = (const float*)d_in[4];
  const float* fc_w = (const float*)d_in[5];
  const float* fc_b = (const float*)d_in[6];
  float* out = (float*)d_out;

  int*   cnt  = (int*)d_ws;                      // 8 groups x 64 B
  short* hbuf = (short*)((char*)d_ws + 512);     // 2 x 128 x 512 bf16 = 256 KB

  hipMemsetAsync(d_ws, 0, 512, stream);                  // zero counters
  hipMemsetAsync(d_out, 0, Bn * sizeof(float), stream);  // out accumulated via atomics

  lstm_persist<<<dim3(PM * PN), dim3(256), 0, stream>>>(
      x, W_ih, W_hh, b_ih, b_hh, fc_w, fc_b, out, cnt, hbuf);
}

// Round 2
// 3768.518 us; speedup vs baseline: 2.5076x; 2.5076x over previous
//
#include <hip/hip_runtime.h>
#include <stdint.h>
#include <stddef.h>

// LSTM_63488206569533: B=128, T=1024, I=256, H=512, fp32 in/out.
// Persistent kernel: 256 WGs (8 batch-groups x 32 unit-slices), one per CU.
// Each WG: 16 batches x 16 hidden units -> 64 gate rows, K=768 (x|h).
// W rows live in MFMA B-fragment registers (bf16).
// R2: h exchanged via relaxed AGENT-scope atomics (sc1 -> LLC-coherent),
// NO fences in the loop (no buffer_wbl2 / buffer_inv bulk cache ops).

#define Bn   128
#define Tn   1024
#define In   256
#define Hn   512
#define PM   8     // batch groups
#define PN   32    // unit slices
#define BPW  16    // batches per WG
#define UPW  16    // units per WG
#define APAD 776   // padded A row length in bf16 elems (1552 B, 16B-aligned rows)

typedef float f4 __attribute__((ext_vector_type(4)));
typedef short s8 __attribute__((ext_vector_type(8)));
typedef unsigned long long u64;

static __device__ __forceinline__ short f2bf(float f) {
  union { float f; unsigned u; } v; v.f = f;
  unsigned u = v.u;
  return (short)((u + 0x7FFFu + ((u >> 16) & 1u)) >> 16);  // RNE
}

__global__ __launch_bounds__(256, 1)
void lstm_persist(const float* __restrict__ x,
                  const float* __restrict__ W_ih,
                  const float* __restrict__ W_hh,
                  const float* __restrict__ b_ih,
                  const float* __restrict__ b_hh,
                  const float* __restrict__ fc_w,
                  const float* __restrict__ fc_b,
                  float* __restrict__ out,
                  int* __restrict__ cnt,     // [PM] padded to 64B each
                  short* __restrict__ hbuf)  // [2][Bn][Hn] bf16 bits
{
  const int tid  = threadIdx.x;
  const int wave = tid >> 6;    // 0..3  == gate type (i,f,g,o)
  const int lane = tid & 63;
  const int n16  = lane & 15;   // MFMA: batch row (A) / gate col (B)
  const int q    = lane >> 4;   // MFMA quad -> k-subblock
  const int bg   = blockIdx.x & 7;   // batch group
  const int ns   = blockIdx.x >> 3;  // unit slice 0..31

  __shared__ short A_lds[16 * APAD];      // [batch 16][k 768(+pad)] bf16
  __shared__ float gate_lds[4 * 256];     // [gate 4][batch 16][unit 16]

  // ---- one-time: preload this wave's 16 W rows into B-fragments (bf16) ----
  s8 bfrag[24];
  {
    const int grow = wave * Hn + ns * UPW + n16;  // global gate row in [0,4H)
#pragma unroll
    for (int kk = 0; kk < 24; ++kk) {
      const float* p = (kk < 8)
        ? (W_ih + (size_t)grow * In + kk * 32 + q * 8)
        : (W_hh + (size_t)grow * Hn + (kk - 8) * 32 + q * 8);
      f4 lo = ((const f4*)p)[0];
      f4 hi = ((const f4*)p)[1];
      s8 b;
      b[0]=f2bf(lo[0]); b[1]=f2bf(lo[1]); b[2]=f2bf(lo[2]); b[3]=f2bf(lo[3]);
      b[4]=f2bf(hi[0]); b[5]=f2bf(hi[1]); b[6]=f2bf(hi[2]); b[7]=f2bf(hi[3]);
      bfrag[kk] = b;
    }
  }

  // ---- elementwise-phase mapping: tid -> (batch em, unit en) ----
  const int em  = tid >> 4;
  const int en  = tid & 15;
  const int ug  = ns * UPW + en;     // global unit
  const int bgl = bg * BPW + em;     // global batch
  const float bia = b_ih[ug]        + b_hh[ug];
  const float bfa = b_ih[Hn + ug]   + b_hh[Hn + ug];
  const float bga = b_ih[2*Hn + ug] + b_hh[2*Hn + ug];
  const float boa = b_ih[3*Hn + ug] + b_hh[3*Hn + ug];

  int*   mycnt = cnt + bg * 16;      // 64B-padded per group, monotonic
  short* hb0   = hbuf;
  short* hb1   = hbuf + Bn * Hn;

  const float* xbase = x + (size_t)bgl * Tn * In + en * 16;
  const short* aptr  = A_lds + n16 * APAD + q * 8;

  float creg = 0.f, hreg = 0.f;

  for (int t = 0; t < Tn; ++t) {
    // (1) stage x_t -> A_lds[:, 0:256] (fp32 -> bf16); normal cached loads
    {
      const f4* xp = (const f4*)(xbase + (size_t)t * In);
      f4 a = xp[0], b = xp[1], c = xp[2], d = xp[3];
      s8 lo, hi;
      lo[0]=f2bf(a[0]); lo[1]=f2bf(a[1]); lo[2]=f2bf(a[2]); lo[3]=f2bf(a[3]);
      lo[4]=f2bf(b[0]); lo[5]=f2bf(b[1]); lo[6]=f2bf(b[2]); lo[7]=f2bf(b[3]);
      hi[0]=f2bf(c[0]); hi[1]=f2bf(c[1]); hi[2]=f2bf(c[2]); hi[3]=f2bf(c[3]);
      hi[4]=f2bf(d[0]); hi[5]=f2bf(d[1]); hi[6]=f2bf(d[2]); hi[7]=f2bf(d[3]);
      s8* dst = (s8*)(A_lds + em * APAD + en * 16);
      dst[0] = lo; dst[1] = hi;
    }
    __syncthreads();

    // (2) x-part MFMAs while (possibly) waiting on producers
    f4 acc = {0.f, 0.f, 0.f, 0.f};
#pragma unroll
    for (int kk = 0; kk < 8; ++kk) {
      s8 a = *(const s8*)(aptr + kk * 32);
      acc = __builtin_amdgcn_mfma_f32_16x16x32_bf16(a, bfrag[kk], acc, 0, 0, 0);
    }

    if (t > 0) {
      // (3) wait for all 32 slices of this batch group to have posted h_t.
      // Relaxed agent poll (LLC); NO acquire fence (no buffer_inv).
      if (tid == 0) {
        const int target = PN * t;
        while (__hip_atomic_load(mycnt, __ATOMIC_RELAXED, __HIP_MEMORY_SCOPE_AGENT) < target)
          __builtin_amdgcn_s_sleep(1);
      }
      __syncthreads();
      // (4) stage h_t -> A_lds[:, 256:768] via relaxed agent atomic loads
      //     (global_load_dwordx2 sc1 -> served at the coherent point/LLC)
      {
        const short* hcur = ((t & 1) ? hb1 : hb0);
        const u64* hp = (const u64*)(hcur + (size_t)bgl * Hn + en * 32);
        u64 v0 = __hip_atomic_load(hp + 0, __ATOMIC_RELAXED, __HIP_MEMORY_SCOPE_AGENT);
        u64 v1 = __hip_atomic_load(hp + 1, __ATOMIC_RELAXED, __HIP_MEMORY_SCOPE_AGENT);
        u64 v2 = __hip_atomic_load(hp + 2, __ATOMIC_RELAXED, __HIP_MEMORY_SCOPE_AGENT);
        u64 v3 = __hip_atomic_load(hp + 3, __ATOMIC_RELAXED, __HIP_MEMORY_SCOPE_AGENT);
        u64 v4 = __hip_atomic_load(hp + 4, __ATOMIC_RELAXED, __HIP_MEMORY_SCOPE_AGENT);
        u64 v5 = __hip_atomic_load(hp + 5, __ATOMIC_RELAXED, __HIP_MEMORY_SCOPE_AGENT);
        u64 v6 = __hip_atomic_load(hp + 6, __ATOMIC_RELAXED, __HIP_MEMORY_SCOPE_AGENT);
        u64 v7 = __hip_atomic_load(hp + 7, __ATOMIC_RELAXED, __HIP_MEMORY_SCOPE_AGENT);
        u64* dst = (u64*)(A_lds + em * APAD + 256 + en * 32);
        dst[0] = v0; dst[1] = v1; dst[2] = v2; dst[3] = v3;
        dst[4] = v4; dst[5] = v5; dst[6] = v6; dst[7] = v7;
      }
      __syncthreads();
      // (5) h-part MFMAs
#pragma unroll
      for (int kk = 8; kk < 24; ++kk) {
        s8 a = *(const s8*)(aptr + kk * 32);
        acc = __builtin_amdgcn_mfma_f32_16x16x32_bf16(a, bfrag[kk], acc, 0, 0, 0);
      }
    }
    // t==0: h_0 == 0, recurrent contribution is zero -> skip entirely.

    // (6) exchange gates through LDS (C-layout: row=(q*4+r)=batch, col=n16=unit)
#pragma unroll
    for (int r = 0; r < 4; ++r)
      gate_lds[wave * 256 + (q * 4 + r) * 16 + n16] = acc[r];
    __syncthreads();

    // (7) per-(batch,unit) LSTM cell update; c stays in a register
    {
      float zi = gate_lds[tid]       + bia;
      float zf = gate_lds[256 + tid] + bfa;
      float zg = gate_lds[512 + tid] + bga;
      float zo = gate_lds[768 + tid] + boa;
      float gi = 1.f / (1.f + __expf(-zi));
      float gf = 1.f / (1.f + __expf(-zf));
      float gg = 2.f / (1.f + __expf(-2.f * zg)) - 1.f;   // tanh
      float go = 1.f / (1.f + __expf(-zo));
      creg = gf * creg + gi * gg;
      float tc = 2.f / (1.f + __expf(-2.f * creg)) - 1.f; // tanh(c)
      hreg = go * tc;
      // pack 2 adjacent units (en even -> lo, en odd -> hi) into one dword and
      // store via relaxed agent atomic (global_store_dword sc1 -> LLC).
      unsigned hb = (unsigned short)f2bf(hreg);
      unsigned ob = (unsigned)__shfl_xor((int)hb, 1, 64);
      if (!(en & 1)) {
        unsigned packed = hb | (ob << 16);
        short* hnxt = (((t + 1) & 1) ? hb1 : hb0);
        unsigned* hw = (unsigned*)hnxt + (size_t)bgl * (Hn / 2) + ((unsigned)ug >> 1);
        __hip_atomic_store(hw, packed, __ATOMIC_RELAXED, __HIP_MEMORY_SCOPE_AGENT);
      }
    }
    __syncthreads();  // s_barrier is preceded by s_waitcnt vmcnt(0): all h-stores acked
    if (tid == 0) {
      // NO release fence (no buffer_wbl2): stores are already agent-coherent.
      __hip_atomic_fetch_add(mycnt, 1, __ATOMIC_RELAXED, __HIP_MEMORY_SCOPE_AGENT);
    }
  }

  // ---- epilogue: out[b] = sum_u hT[b,u] * fc_w[u] + fc_b ----
  float partial = hreg * fc_w[ug];
#pragma unroll
  for (int off = 1; off < 16; off <<= 1)
    partial += __shfl_xor(partial, off, 64);   // reduce over the 16 units
  if (en == 0) {
    if (ns == 0) partial += fc_b[0];           // fc_b exactly once per batch
    atomicAdd(&out[bgl], partial);
  }
}

extern "C" void kernel_launch(void* const* d_in, const int* in_sizes, int n_in,
                              void* d_out, int out_size, void* d_ws, size_t ws_size,
                              hipStream_t stream) {
  const float* x    = (const float*)d_in[0];
  const float* W_ih = (const float*)d_in[1];
  const float* W_hh = (const float*)d_in[2];
  const float* b_ih = (const float*)d_in[3];
  const float* b_hh = (const float*)d_in[4];
  const float* fc_w = (const float*)d_in[5];
  const float* fc_b = (const float*)d_in[6];
  float* out = (float*)d_out;

  int*   cnt  = (int*)d_ws;                      // 8 groups x 64 B
  short* hbuf = (short*)((char*)d_ws + 512);     // 2 x 128 x 512 bf16 = 256 KB

  hipMemsetAsync(d_ws, 0, 512, stream);                  // zero counters
  hipMemsetAsync(d_out, 0, Bn * sizeof(float), stream);  // out accumulated via atomics

  lstm_persist<<<dim3(PM * PN), dim3(256), 0, stream>>>(
      x, W_ih, W_hh, b_ih, b_hh, fc_w, fc_b, out, cnt, hbuf);
}